// Round 24
// baseline (130.868 us; speedup 1.0000x reference)
//
#include <hip/hip_runtime.h>

typedef __bf16 bf16;
typedef __bf16 bf16x8 __attribute__((ext_vector_type(8)));
typedef __bf16 bf16x4 __attribute__((ext_vector_type(4)));
typedef float f32x4 __attribute__((ext_vector_type(4)));
typedef float f32x16 __attribute__((ext_vector_type(16)));
typedef float fx2 __attribute__((ext_vector_type(2)));

#define DEV static __device__ __forceinline__

constexpr int BB = 2, SS = 2048, DM = 1024, NH = 16, HD = 64;
constexpr int MTOT = BB * SS;  // 4096
constexpr float LOG2E = 1.4426950408889634f;

// ---- workspace layout (bytes) ----
constexpr size_t OFF_XB   = 0;                                  // bf16 [4096][1024]
constexpr size_t OFF_WQKV = OFF_XB   + (size_t)MTOT * DM * 2;   // bf16 [3072][1024]
constexpr size_t OFF_WO   = OFF_WQKV + (size_t)3 * DM * DM * 2; // bf16 [1024][1024]
constexpr size_t OFF_TAB  = OFF_WO   + (size_t)DM * DM * 2;     // fx2  [2048][32]
constexpr size_t OFF_Q    = OFF_TAB  + (size_t)SS * (HD/2) * 8; // bf16 (B,H,S,d)
constexpr size_t OFF_KF   = OFF_Q    + (size_t)MTOT * DM * 2;   // bf16 pre-fragmented K
constexpr size_t OFF_VF   = OFF_KF   + (size_t)MTOT * DM * 2;   // bf16 pre-fragmented V
constexpr size_t OFF_AO   = OFF_VF   + (size_t)MTOT * DM * 2;   // bf16 [4096][1024]

typedef const __attribute__((address_space(1))) void gas_void;
typedef __attribute__((address_space(3))) void las_void;

DEV void gload16(const bf16* g, bf16* l) {
  __builtin_amdgcn_global_load_lds((gas_void*)g, (las_void*)l, 16, 0, 0);
}

DEV f32x4 mfma16(bf16x8 a, bf16x8 b, f32x4 c) {
  return __builtin_amdgcn_mfma_f32_16x16x32_bf16(a, b, c, 0, 0, 0);
}

DEV f32x16 mfma32(bf16x8 a, bf16x8 b, f32x16 c) {
  return __builtin_amdgcn_mfma_f32_32x32x16_bf16(a, b, c, 0, 0, 0);
}

DEV unsigned pack2(float a, float b) {
  union { bf16 h[2]; unsigned u; } cv;
  cv.h[0] = (bf16)a; cv.h[1] = (bf16)b;
  return cv.u;
}

// ---------------- prep: fp32 -> bf16 casts + RoPE table ----------------
__global__ void prep_kernel(const float* __restrict__ x, const float* __restrict__ wq,
    const float* __restrict__ wk, const float* __restrict__ wv, const float* __restrict__ wo,
    const int* __restrict__ pos, bf16* __restrict__ xb, bf16* __restrict__ wqkv,
    bf16* __restrict__ wob, fx2* __restrict__ tab) {
  const int NX4 = MTOT * DM / 4;     // 1048576
  const int NW4 = DM * DM / 4;       // 262144 = 2^18
  const int TOTC = NX4 + 4 * NW4;    // 2097152
  const int NTAB = SS * (HD / 2);    // 65536
  const int total = TOTC + NTAB;
  for (int i = blockIdx.x * blockDim.x + threadIdx.x; i < total; i += gridDim.x * blockDim.x) {
    if (i < TOTC) {
      const float* src; bf16* dst; int off;
      if (i < NX4) { src = x; dst = xb; off = i; }
      else {
        int i2 = i - NX4; int which = i2 >> 18; off = i2 & (NW4 - 1);
        src = which == 0 ? wq : which == 1 ? wk : which == 2 ? wv : wo;
        dst = which == 0 ? wqkv : which == 1 ? wqkv + DM * DM : which == 2 ? wqkv + 2 * DM * DM : wob;
      }
      float4 v = ((const float4*)src)[off];
      bf16x4 o4 = { (bf16)v.x, (bf16)v.y, (bf16)v.z, (bf16)v.w };
      ((bf16x4*)dst)[off] = o4;
    } else {
      int e = i - TOTC;
      int s = e >> 5, p = e & 31;
      float invf = __builtin_exp2f(-(float)p * (13.287712379549449f / 32.0f));
      float ang = (float)pos[s] * invf;
      fx2 cs; cs.x = cosf(ang); cs.y = sinf(ang);
      tab[e] = cs;
    }
  }
}

// ---- 128x128 bf16 GEMM mainloop, 3-buffer ring + counted vmcnt (T3+T4).
DEV void gemm_bt_128(const bf16* __restrict__ A, const bf16* __restrict__ Bw,
                     int rowA0, int rowB0, f32x4 (&acc)[4][4], bf16* lds) {
  const int t = threadIdx.x, w = t >> 6, lane = t & 63;
  const int wr = w >> 1, wc = w & 1, g = lane >> 4, c = lane & 15;
#pragma unroll
  for (int mi = 0; mi < 4; mi++)
#pragma unroll
    for (int ni = 0; ni < 4; ni++) acc[mi][ni] = (f32x4){0.f, 0.f, 0.f, 0.f};
  const bf16* ga = A + (size_t)(rowA0 + (t >> 2)) * DM + (t & 3) * 8;
  const bf16* gb = Bw + (size_t)(rowB0 + (t >> 2)) * DM + (t & 3) * 8;
  const int arow = wr * 64 + c, brow = wc * 64 + c;
  auto stage = [&](int k0, int buf) {
    bf16* la = lds + buf * 8192 + w * 512;        // wave-uniform base
    bf16* lb = lds + buf * 8192 + 4096 + w * 512;
    gload16(ga + k0,            la);
    gload16(ga + k0 + 64 * DM,  la + 2048);
    gload16(gb + k0,            lb);
    gload16(gb + k0 + 64 * DM,  lb + 2048);
  };
  stage(0, 0);
  stage(32, 1);
  asm volatile("s_waitcnt vmcnt(4)" ::: "memory");   // tile 0 landed (mine)
  __builtin_amdgcn_s_barrier();                      // cross-wave: tile 0 ready
  __builtin_amdgcn_sched_barrier(0);
  for (int it = 0; it < 32; ++it) {
    const int cur = it % 3;
    const bf16* lA = lds + cur * 8192;
    const bf16* lB = lds + cur * 8192 + 4096;
    bf16x8 af[4], bf_[4];
#pragma unroll
    for (int mi = 0; mi < 4; mi++) af[mi]  = *(const bf16x8*)(lA + (arow + mi * 16) * 32 + g * 8);
#pragma unroll
    for (int ni = 0; ni < 4; ni++) bf_[ni] = *(const bf16x8*)(lB + (brow + ni * 16) * 32 + g * 8);
#pragma unroll
    for (int mi = 0; mi < 4; mi++)
#pragma unroll
      for (int ni = 0; ni < 4; ni++)
        acc[mi][ni] = mfma16(af[mi], bf_[ni], acc[mi][ni]);
    // stage tile t+2 into buf (t+2)%3 (last read at iter t-1, fenced by its barrier)
    if (it + 2 < 32) stage((it + 2) * 32, (it + 2) % 3);
    if (it + 1 < 32) {
      if (it + 2 < 32) asm volatile("s_waitcnt vmcnt(4)" ::: "memory");  // t+1 landed
      else             asm volatile("s_waitcnt vmcnt(0)" ::: "memory");  // final tile
      __builtin_amdgcn_s_barrier();
      __builtin_amdgcn_sched_barrier(0);
    }
  }
}

// ---------------- QKV projection + RoPE epilogue (LDS re-layout, coalesced out) ----
__global__ __launch_bounds__(256, 3) void qkv_kernel(const bf16* __restrict__ xb,
    const bf16* __restrict__ wqkv, const fx2* __restrict__ tab,
    bf16* __restrict__ Qb, bf16* __restrict__ KFb, bf16* __restrict__ VFb) {
  __shared__ __align__(16) bf16 L[24576];            // 48KB: 3-buf gemm ring
  f32x4 acc[4][4];
  const int rowA0 = blockIdx.y * 128, rowB0 = blockIdx.x * 128;
  gemm_bt_128(xb, wqkv, rowA0, rowB0, acc, L);
  const int t = threadIdx.x, w = t >> 6, lane = t & 63;
  const int wr = w >> 1, wc = w & 1, g = lane >> 4, c = lane & 15;
  const int which = rowB0 >> 10;
  const int b = rowA0 >> 11;
  const int s0 = rowA0 & (SS - 1);
  const int h0 = (rowB0 & (DM - 1)) >> 6;
  const int kt0 = s0 >> 6;
  // last gemm iter reads only buf2; epilogue uses lds[0..16383] -> disjoint.
#pragma unroll
  for (int mi = 0; mi < 4; mi++)
#pragma unroll
    for (int ni = 0; ni < 4; ni++) {
      const int col = wc * 64 + ni * 16 + c;      // 0..127
      const int hh = col >> 6, dd = col & 63;
#pragma unroll
      for (int j = 0; j < 4; j++) {
        const int sp = wr * 64 + mi * 16 + 4 * g + j;   // 0..127
        float v = acc[mi][ni][j];
        int flat;
        if (which < 2) {
          const int s = s0 + sp;
          float partner = __shfl_xor(v, 1);
          fx2 cs = tab[s * 32 + (dd >> 1)];
          v = v * cs.x + ((dd & 1) ? partner : -partner) * cs.y;
          if (which == 0) {
            flat = hh * 8192 + sp * 64 + dd;
          } else {
            const int spp = sp & 63;
            flat = (hh * 2 + (sp >> 6)) * 4096 +
                   (((spp >> 5) * 4 + (dd >> 4)) * 64 + (spp & 31) + 32 * ((dd >> 3) & 1)) * 8 +
                   (dd & 7);
          }
        } else {
          const int spp = sp & 63;   // = mi*16 + 4g + j
          flat = (hh * 2 + (sp >> 6)) * 4096 +
                 (((dd >> 5) * 4 + mi) * 64 + (dd & 31) + 32 * (g >> 1)) * 8 + (spp & 7);
        }
        L[flat] = (bf16)v;
      }
    }
  __syncthreads();
  if (which == 0) {
    bf16* base0 = Qb + ((size_t)(b * NH + h0) * SS + s0) * HD;
    bf16* base1 = Qb + ((size_t)(b * NH + h0 + 1) * SS + s0) * HD;
#pragma unroll
    for (int j2 = 0; j2 < 8; j2++) {
      const int off = j2 * 2048 + t * 8;
      bf16* dst = (off < 8192 ? base0 : base1) + (off & 8191);
      *(bf16x8*)dst = *(const bf16x8*)(L + off);
    }
  } else {
    bf16* outp = (which == 1) ? KFb : VFb;
#pragma unroll
    for (int j2 = 0; j2 < 8; j2++) {
      const int off = j2 * 2048 + t * 8;
      const int r = off >> 12;                 // 0..3 = h'*2 + kt'
      bf16* dst = outp + ((size_t)(b * NH + h0 + (r >> 1)) * 32 + kt0 + (r & 1)) * 4096 + (off & 4095);
      *(bf16x8*)dst = *(const bf16x8*)(L + off);
    }
  }
}

// ---------------- flash attention (causal), swapped 32x32, 4-wave split-k ----------------
// R20 structure (best: no LDS in k-loop, contiguous KF/VF 1KB loads, KVBLK=64,
// 4-wave split-k, launch_bounds(256,3)) + softmax micro-opts:
//  (a) l-sum on the MFMA pipe: lacc = mfma32(ones, pf[ks], lacc) -> lacc[0] =
//      sum_k P[k][q] (C col = lane&31 = q; all rows identical). Removes the
//      31-add sum tree + cross-shuffle per visit from the VALU critical path.
//  (b) max reduce via nested 3-input fmax (fuses to v_max3_f32).
__global__ __launch_bounds__(256, 3) void attn_kernel(const bf16* __restrict__ Q,
    const bf16* __restrict__ KF, const bf16* __restrict__ VF, bf16* __restrict__ AO) {
  __shared__ float Om[3][2048];   // [64 d-rows][32 q-cols] per publishing wave
  __shared__ float Ml[3][32];
  __shared__ float Ll[3][32];
  const int flat = blockIdx.x;                       // 0..1023
  const int flat2 = (flat & 7) * 128 + (flat >> 3);  // XCD-contiguous
  const int bh = flat2 >> 5;                         // 0..31 (4 per XCD)
  const int p = flat2 & 31;                          // pair index
  const int w = threadIdx.x >> 6;                    // wave 0..3
  const int lane = threadIdx.x & 63;
  const int q31 = lane & 31, hi = lane >> 5;
  const bf16* Qp = Q + (size_t)bh * SS * HD;
  const bf16* KFp = KF + (size_t)bh * SS * HD;       // 131072 bf16 per bh
  const bf16* VFp = VF + (size_t)bh * SS * HD;
  const float SCL = 0.125f * LOG2E;                  // exp2-domain scale
  bf16x8 onesA;
#pragma unroll
  for (int e = 0; e < 8; e++) onesA[e] = (bf16)1.0f;

  auto run_chunk = [&](int qbase, int nt) {
    // Q frags (B-operand): lane: Q[qbase+q31][ds*16 + hi*8 + e], scaled
    bf16x8 qb[4];
#pragma unroll
    for (int ds = 0; ds < 4; ds++) {
      bf16x8 xq = *(const bf16x8*)(Qp + (size_t)(qbase + q31) * HD + ds * 16 + hi * 8);
#pragma unroll
      for (int e = 0; e < 8; e++) xq[e] = (bf16)((float)xq[e] * SCL);
      qb[ds] = xq;
    }
    float m_r = -3.0e38f;
    f32x16 o0, o1, lacc;
#pragma unroll
    for (int e = 0; e < 16; e++) { o0[e] = 0.f; o1[e] = 0.f; lacc[e] = 0.f; }

    for (int tv = w; tv < nt; tv += 4) {
      const int k0 = tv * 64;
      const bf16* kt = KFp + (size_t)tv * 4096;
      const bf16* vt = VFp + (size_t)tv * 4096;
      // ---- QK^T (swapped: A=K, B=Q), K frags loaded 4-at-a-time ----
      f32x16 s0, s1;
#pragma unroll
      for (int e = 0; e < 16; e++) { s0[e] = 0.f; s1[e] = 0.f; }
      {
        bf16x8 kf[4];
#pragma unroll
        for (int ds = 0; ds < 4; ds++)
          kf[ds] = *(const bf16x8*)(kt + (size_t)(ds * 64 + lane) * 8);
#pragma unroll
        for (int ds = 0; ds < 4; ds++) s0 = mfma32(kf[ds], qb[ds], s0);
#pragma unroll
        for (int ds = 0; ds < 4; ds++)
          kf[ds] = *(const bf16x8*)(kt + (size_t)((4 + ds) * 64 + lane) * 8);
#pragma unroll
        for (int ds = 0; ds < 4; ds++) s1 = mfma32(kf[ds], qb[ds], s1);
      }
      // ---- causal mask (diagonal tiles only) ----
      if (k0 + 63 > qbase) {
        const int qg = qbase + q31;
#pragma unroll
        for (int r = 0; r < 16; r++) {
          const int kg = k0 + (r & 3) + 8 * (r >> 2) + 4 * hi;
          if (kg > qg)      s0[r] = -1.0e30f;
          if (kg + 32 > qg) s1[r] = -1.0e30f;
        }
      }
      // ---- in-lane online softmax (exp2 domain), max3 tree, defer-max ----
      {
        float a[16];
#pragma unroll
        for (int r = 0; r < 16; r++) a[r] = fmaxf(s0[r], s1[r]);
        const float t0 = fmaxf(fmaxf(a[0], a[1]), a[2]);
        const float t1 = fmaxf(fmaxf(a[3], a[4]), a[5]);
        const float t2 = fmaxf(fmaxf(a[6], a[7]), a[8]);
        const float t3 = fmaxf(fmaxf(a[9], a[10]), a[11]);
        const float t4 = fmaxf(fmaxf(a[12], a[13]), a[14]);
        const float u0 = fmaxf(fmaxf(t0, t1), t2);
        const float u1 = fmaxf(fmaxf(t3, t4), a[15]);
        const float pm0 = fmaxf(u0, u1);
        const float pm = fmaxf(pm0, __shfl_xor(pm0, 32));
        if (__any(pm > m_r + 8.0f)) {            // T13 defer-max, THR=8
          const float mnew = fmaxf(m_r, pm);
          const float alpha = __builtin_exp2f(m_r - mnew);
          lacc[0] *= alpha;                      // only element 0 is read
#pragma unroll
          for (int e = 0; e < 16; e++) { o0[e] *= alpha; o1[e] *= alpha; }
          m_r = mnew;
        }
#pragma unroll
        for (int r = 0; r < 16; r++) {
          s0[r] = __builtin_exp2f(s0[r] - m_r);
          s1[r] = __builtin_exp2f(s1[r] - m_r);
        }
      }
      // ---- pack P into B-frags (16 pack2 + 8 shfl_xor(32)) ----
      bf16x8 pf[4];
#pragma unroll
      for (int ks = 0; ks < 4; ks++) {
        const int rb = 8 * (ks & 1);
        float va0, va1, va2, va3, vb0, vb1, vb2, vb3;
        if (ks < 2) {
          va0 = s0[rb]; va1 = s0[rb + 1]; va2 = s0[rb + 2]; va3 = s0[rb + 3];
          vb0 = s0[rb + 4]; vb1 = s0[rb + 5]; vb2 = s0[rb + 6]; vb3 = s0[rb + 7];
        } else {
          va0 = s1[rb]; va1 = s1[rb + 1]; va2 = s1[rb + 2]; va3 = s1[rb + 3];
          vb0 = s1[rb + 4]; vb1 = s1[rb + 5]; vb2 = s1[rb + 6]; vb3 = s1[rb + 7];
        }
        const unsigned a01 = pack2(va0, va1), a23 = pack2(va2, va3);
        const unsigned b01 = pack2(vb0, vb1), b23 = pack2(vb2, vb3);
        const unsigned z1 = (unsigned)__shfl_xor((int)(hi ? a01 : b01), 32);
        const unsigned z2 = (unsigned)__shfl_xor((int)(hi ? a23 : b23), 32);
        union { unsigned u[4]; bf16x8 v; } cv;
        cv.u[0] = hi ? z1 : a01;
        cv.u[1] = hi ? z2 : a23;
        cv.u[2] = hi ? b01 : z1;
        cv.u[3] = hi ? b23 : z2;
        pf[ks] = cv.v;
      }
      // ---- l-sum on the MFMA pipe: lacc[0] += sum_k P[k][q] ----
#pragma unroll
      for (int ks = 0; ks < 4; ks++) lacc = mfma32(onesA, pf[ks], lacc);
      // ---- PV (swapped: A=V, B=P); V frags loaded per-dt half ----
      {
        bf16x8 vf[4];
#pragma unroll
        for (int ks = 0; ks < 4; ks++)
          vf[ks] = *(const bf16x8*)(vt + (size_t)(ks * 64 + lane) * 8);
#pragma unroll
        for (int ks = 0; ks < 4; ks++) o0 = mfma32(vf[ks], pf[ks], o0);
#pragma unroll
        for (int ks = 0; ks < 4; ks++)
          vf[ks] = *(const bf16x8*)(vt + (size_t)((4 + ks) * 64 + lane) * 8);
#pragma unroll
        for (int ks = 0; ks < 4; ks++) o1 = mfma32(vf[ks], pf[ks], o1);
      }
    }
    const float lsum = lacc[0];
    // ---- publish partials (waves 1..3), merge + store (wave 0) ----
    __syncthreads();
    if (w) {
#pragma unroll
      for (int e = 0; e < 16; e++) {
        const int r = (e & 3) + 8 * (e >> 2) + 4 * hi;
        Om[w - 1][r * 32 + q31] = o0[e];
        Om[w - 1][(r + 32) * 32 + q31] = o1[e];
      }
      if (!hi) { Ml[w - 1][q31] = m_r; Ll[w - 1][q31] = lsum; }
    }
    __syncthreads();
    if (!w) {
      float mi_[3];
#pragma unroll
      for (int i = 0; i < 3; i++) mi_[i] = Ml[i][q31];
      float mm = fmaxf(fmaxf(m_r, mi_[0]), fmaxf(mi_[1], mi_[2]));
      const float aS = __builtin_exp2f(m_r - mm);
      float ai[3];
      float L2 = aS * lsum;
#pragma unroll
      for (int i = 0; i < 3; i++) {
        ai[i] = __builtin_exp2f(mi_[i] - mm);
        L2 += ai[i] * Ll[i][q31];
      }
      const float linv = 1.0f / L2;
      const int b = bh >> 4, h = bh & 15;
      const size_t rowb = ((size_t)(b * SS + qbase + q31)) * DM + h * HD;
#pragma unroll
      for (int g2 = 0; g2 < 4; g2++) {
        bf16x4 w0v, w1v;
#pragma unroll
        for (int j = 0; j < 4; j++) {
          const int e = 4 * g2 + j;
          const int r = j + 8 * g2 + 4 * hi;
          float v0 = aS * o0[e];
          float v1 = aS * o1[e];
#pragma unroll
          for (int i = 0; i < 3; i++) {
            v0 += ai[i] * Om[i][r * 32 + q31];
            v1 += ai[i] * Om[i][(r + 32) * 32 + q31];
          }
          w0v[j] = (bf16)(v0 * linv);
          w1v[j] = (bf16)(v1 * linv);
        }
        *(bf16x4*)(AO + rowb +      8 * g2 + 4 * hi) = w0v;
        *(bf16x4*)(AO + rowb + 32 + 8 * g2 + 4 * hi) = w1v;
      }
    }
    __syncthreads();   // protect merge buffers before next chunk's publishes
  };

  // pair p & 63-p: 33 tiles total per block, uniform across all blocks
  run_chunk(p * 32, p / 2 + 1);
  const int ph = 63 - p;
  run_chunk(ph * 32, ph / 2 + 1);
}

// ---------------- output projection -> fp32 d_out ----------------
__global__ __launch_bounds__(256, 2) void oproj_kernel(const bf16* __restrict__ AO,
    const bf16* __restrict__ wob, float* __restrict__ out) {
  __shared__ __align__(16) bf16 L[24576];
  f32x4 acc[4][4];
  const int rowA0 = blockIdx.y * 128, rowB0 = blockIdx.x * 128;
  gemm_bt_128(AO, wob, rowA0, rowB0, acc, L);
  const int t = threadIdx.x, w = t >> 6, lane = t & 63;
  const int wr = w >> 1, wc = w & 1, g = lane >> 4, c = lane & 15;
#pragma unroll
  for (int mi = 0; mi < 4; mi++)
#pragma unroll
    for (int ni = 0; ni < 4; ni++) {
      const int ncol = rowB0 + wc * 64 + ni * 16 + c;
#pragma unroll
      for (int j = 0; j < 4; j++) {
        const int mrow = rowA0 + wr * 64 + mi * 16 + 4 * g + j;
        out[(size_t)mrow * DM + ncol] = acc[mi][ni][j];
      }
    }
}

extern "C" void kernel_launch(void* const* d_in, const int* in_sizes, int n_in,
                              void* d_out, int out_size, void* d_ws, size_t ws_size,
                              hipStream_t stream) {
  const float* x  = (const float*)d_in[0];
  const float* wq = (const float*)d_in[1];
  const float* wk = (const float*)d_in[2];
  const float* wv = (const float*)d_in[3];
  const float* wo = (const float*)d_in[4];
  const int*   pos = (const int*)d_in[5];
  char* ws = (char*)d_ws;
  bf16* xb   = (bf16*)(ws + OFF_XB);
  bf16* wqkv = (bf16*)(ws + OFF_WQKV);
  bf16* wob  = (bf16*)(ws + OFF_WO);
  fx2*  tab  = (fx2*)(ws + OFF_TAB);
  bf16* Qb   = (bf16*)(ws + OFF_Q);
  bf16* KFb  = (bf16*)(ws + OFF_KF);
  bf16* VFb  = (bf16*)(ws + OFF_VF);
  bf16* AOb  = (bf16*)(ws + OFF_AO);

  hipLaunchKernelGGL(prep_kernel, dim3(2048), dim3(256), 0, stream,
                     x, wq, wk, wv, wo, pos, xb, wqkv, wob, tab);
  hipLaunchKernelGGL(qkv_kernel, dim3(24, 32), dim3(256), 0, stream,
                     xb, wqkv, tab, Qb, KFb, VFb);
  hipLaunchKernelGGL(attn_kernel, dim3(1024), dim3(256), 0, stream,
                     Qb, KFb, VFb, AOb);
  hipLaunchKernelGGL(oproj_kernel, dim3(8, 32), dim3(256), 0, stream,
                     AOb, wob, (float*)d_out);
}

// Round 25
// 117.775 us; speedup vs baseline: 1.1112x; 1.1112x over previous
//
#include <hip/hip_runtime.h>

typedef __bf16 bf16;
typedef __bf16 bf16x8 __attribute__((ext_vector_type(8)));
typedef __bf16 bf16x4 __attribute__((ext_vector_type(4)));
typedef float f32x4 __attribute__((ext_vector_type(4)));
typedef float f32x16 __attribute__((ext_vector_type(16)));
typedef float fx2 __attribute__((ext_vector_type(2)));

#define DEV static __device__ __forceinline__

constexpr int BB = 2, SS = 2048, DM = 1024, NH = 16, HD = 64;
constexpr int MTOT = BB * SS;  // 4096
constexpr float LOG2E = 1.4426950408889634f;

// ---- workspace layout (bytes) ----
constexpr size_t OFF_XB   = 0;                                  // bf16 [4096][1024]
constexpr size_t OFF_WQKV = OFF_XB   + (size_t)MTOT * DM * 2;   // bf16 [3072][1024]
constexpr size_t OFF_WO   = OFF_WQKV + (size_t)3 * DM * DM * 2; // bf16 [1024][1024]
constexpr size_t OFF_TAB  = OFF_WO   + (size_t)DM * DM * 2;     // fx2  [2048][32]
constexpr size_t OFF_Q    = OFF_TAB  + (size_t)SS * (HD/2) * 8; // bf16 (B,H,S,d)
constexpr size_t OFF_KF   = OFF_Q    + (size_t)MTOT * DM * 2;   // bf16 pre-fragmented K
constexpr size_t OFF_VF   = OFF_KF   + (size_t)MTOT * DM * 2;   // bf16 pre-fragmented V
constexpr size_t OFF_AO   = OFF_VF   + (size_t)MTOT * DM * 2;   // bf16 [4096][1024]

typedef const __attribute__((address_space(1))) void gas_void;
typedef __attribute__((address_space(3))) void las_void;

DEV void gload16(const bf16* g, bf16* l) {
  __builtin_amdgcn_global_load_lds((gas_void*)g, (las_void*)l, 16, 0, 0);
}

DEV f32x4 mfma16(bf16x8 a, bf16x8 b, f32x4 c) {
  return __builtin_amdgcn_mfma_f32_16x16x32_bf16(a, b, c, 0, 0, 0);
}

DEV f32x16 mfma32(bf16x8 a, bf16x8 b, f32x16 c) {
  return __builtin_amdgcn_mfma_f32_32x32x16_bf16(a, b, c, 0, 0, 0);
}

DEV unsigned pack2(float a, float b) {
  union { bf16 h[2]; unsigned u; } cv;
  cv.h[0] = (bf16)a; cv.h[1] = (bf16)b;
  return cv.u;
}

// ---------------- prep: fp32 -> bf16 casts + RoPE table ----------------
__global__ void prep_kernel(const float* __restrict__ x, const float* __restrict__ wq,
    const float* __restrict__ wk, const float* __restrict__ wv, const float* __restrict__ wo,
    const int* __restrict__ pos, bf16* __restrict__ xb, bf16* __restrict__ wqkv,
    bf16* __restrict__ wob, fx2* __restrict__ tab) {
  const int NX4 = MTOT * DM / 4;     // 1048576
  const int NW4 = DM * DM / 4;       // 262144 = 2^18
  const int TOTC = NX4 + 4 * NW4;    // 2097152
  const int NTAB = SS * (HD / 2);    // 65536
  const int total = TOTC + NTAB;
  for (int i = blockIdx.x * blockDim.x + threadIdx.x; i < total; i += gridDim.x * blockDim.x) {
    if (i < TOTC) {
      const float* src; bf16* dst; int off;
      if (i < NX4) { src = x; dst = xb; off = i; }
      else {
        int i2 = i - NX4; int which = i2 >> 18; off = i2 & (NW4 - 1);
        src = which == 0 ? wq : which == 1 ? wk : which == 2 ? wv : wo;
        dst = which == 0 ? wqkv : which == 1 ? wqkv + DM * DM : which == 2 ? wqkv + 2 * DM * DM : wob;
      }
      float4 v = ((const float4*)src)[off];
      bf16x4 o4 = { (bf16)v.x, (bf16)v.y, (bf16)v.z, (bf16)v.w };
      ((bf16x4*)dst)[off] = o4;
    } else {
      int e = i - TOTC;
      int s = e >> 5, p = e & 31;
      float invf = __builtin_exp2f(-(float)p * (13.287712379549449f / 32.0f));
      float ang = (float)pos[s] * invf;
      fx2 cs; cs.x = cosf(ang); cs.y = sinf(ang);
      tab[e] = cs;
    }
  }
}

// ---- 128x128 bf16 GEMM mainloop, 3-buffer ring + counted vmcnt (T3+T4).
//      lds: 24576 bf16 = 48KB, [buf:3][A 4096 | B 4096].
//      Per iter: compute(t) -> stage(t+2) -> s_waitcnt vmcnt(4) (tile t+1
//      landed; t+2 stays in flight) -> raw s_barrier. Never drains to 0
//      mid-loop (the R17/m97 barrier-drain stall).
DEV void gemm_bt_128(const bf16* __restrict__ A, const bf16* __restrict__ Bw,
                     int rowA0, int rowB0, f32x4 (&acc)[4][4], bf16* lds) {
  const int t = threadIdx.x, w = t >> 6, lane = t & 63;
  const int wr = w >> 1, wc = w & 1, g = lane >> 4, c = lane & 15;
#pragma unroll
  for (int mi = 0; mi < 4; mi++)
#pragma unroll
    for (int ni = 0; ni < 4; ni++) acc[mi][ni] = (f32x4){0.f, 0.f, 0.f, 0.f};
  const bf16* ga = A + (size_t)(rowA0 + (t >> 2)) * DM + (t & 3) * 8;
  const bf16* gb = Bw + (size_t)(rowB0 + (t >> 2)) * DM + (t & 3) * 8;
  const int arow = wr * 64 + c, brow = wc * 64 + c;
  auto stage = [&](int k0, int buf) {
    bf16* la = lds + buf * 8192 + w * 512;        // wave-uniform base
    bf16* lb = lds + buf * 8192 + 4096 + w * 512;
    gload16(ga + k0,            la);
    gload16(ga + k0 + 64 * DM,  la + 2048);
    gload16(gb + k0,            lb);
    gload16(gb + k0 + 64 * DM,  lb + 2048);
  };
  stage(0, 0);
  stage(32, 1);
  asm volatile("s_waitcnt vmcnt(4)" ::: "memory");   // tile 0 landed (mine)
  __builtin_amdgcn_s_barrier();                      // cross-wave: tile 0 ready
  __builtin_amdgcn_sched_barrier(0);
  for (int it = 0; it < 32; ++it) {
    const int cur = it % 3;
    const bf16* lA = lds + cur * 8192;
    const bf16* lB = lds + cur * 8192 + 4096;
    bf16x8 af[4], bf_[4];
#pragma unroll
    for (int mi = 0; mi < 4; mi++) af[mi]  = *(const bf16x8*)(lA + (arow + mi * 16) * 32 + g * 8);
#pragma unroll
    for (int ni = 0; ni < 4; ni++) bf_[ni] = *(const bf16x8*)(lB + (brow + ni * 16) * 32 + g * 8);
#pragma unroll
    for (int mi = 0; mi < 4; mi++)
#pragma unroll
      for (int ni = 0; ni < 4; ni++)
        acc[mi][ni] = mfma16(af[mi], bf_[ni], acc[mi][ni]);
    // stage tile t+2 into buf (t+2)%3 (last read at iter t-1, fenced by its barrier)
    if (it + 2 < 32) stage((it + 2) * 32, (it + 2) % 3);
    if (it + 1 < 32) {
      if (it + 2 < 32) asm volatile("s_waitcnt vmcnt(4)" ::: "memory");  // t+1 landed
      else             asm volatile("s_waitcnt vmcnt(0)" ::: "memory");  // final tile
      __builtin_amdgcn_s_barrier();
      __builtin_amdgcn_sched_barrier(0);
    }
  }
}

// ---------------- QKV projection + RoPE epilogue (LDS re-layout, coalesced out) ----
__global__ __launch_bounds__(256, 3) void qkv_kernel(const bf16* __restrict__ xb,
    const bf16* __restrict__ wqkv, const fx2* __restrict__ tab,
    bf16* __restrict__ Qb, bf16* __restrict__ KFb, bf16* __restrict__ VFb) {
  __shared__ __align__(16) bf16 L[24576];            // 48KB: 3-buf gemm ring
  f32x4 acc[4][4];
  const int rowA0 = blockIdx.y * 128, rowB0 = blockIdx.x * 128;
  gemm_bt_128(xb, wqkv, rowA0, rowB0, acc, L);
  const int t = threadIdx.x, w = t >> 6, lane = t & 63;
  const int wr = w >> 1, wc = w & 1, g = lane >> 4, c = lane & 15;
  const int which = rowB0 >> 10;
  const int b = rowA0 >> 11;
  const int s0 = rowA0 & (SS - 1);
  const int h0 = (rowB0 & (DM - 1)) >> 6;
  const int kt0 = s0 >> 6;
  // last gemm iter reads only buf2 (it=31 -> lds[16384..24575]); epilogue
  // re-layout uses lds[0..16383] -> disjoint; __syncthreads orders vs copyout.
#pragma unroll
  for (int mi = 0; mi < 4; mi++)
#pragma unroll
    for (int ni = 0; ni < 4; ni++) {
      const int col = wc * 64 + ni * 16 + c;      // 0..127
      const int hh = col >> 6, dd = col & 63;
#pragma unroll
      for (int j = 0; j < 4; j++) {
        const int sp = wr * 64 + mi * 16 + 4 * g + j;   // 0..127
        float v = acc[mi][ni][j];
        int flat;
        if (which < 2) {
          const int s = s0 + sp;
          float partner = __shfl_xor(v, 1);
          fx2 cs = tab[s * 32 + (dd >> 1)];
          v = v * cs.x + ((dd & 1) ? partner : -partner) * cs.y;
          if (which == 0) {
            flat = hh * 8192 + sp * 64 + dd;
          } else {
            const int spp = sp & 63;
            flat = (hh * 2 + (sp >> 6)) * 4096 +
                   (((spp >> 5) * 4 + (dd >> 4)) * 64 + (spp & 31) + 32 * ((dd >> 3) & 1)) * 8 +
                   (dd & 7);
          }
        } else {
          const int spp = sp & 63;   // = mi*16 + 4g + j
          flat = (hh * 2 + (sp >> 6)) * 4096 +
                 (((dd >> 5) * 4 + mi) * 64 + (dd & 31) + 32 * (g >> 1)) * 8 + (spp & 7);
        }
        L[flat] = (bf16)v;
      }
    }
  __syncthreads();
  if (which == 0) {
    bf16* base0 = Qb + ((size_t)(b * NH + h0) * SS + s0) * HD;
    bf16* base1 = Qb + ((size_t)(b * NH + h0 + 1) * SS + s0) * HD;
#pragma unroll
    for (int j2 = 0; j2 < 8; j2++) {
      const int off = j2 * 2048 + t * 8;
      bf16* dst = (off < 8192 ? base0 : base1) + (off & 8191);
      *(bf16x8*)dst = *(const bf16x8*)(L + off);
    }
  } else {
    bf16* outp = (which == 1) ? KFb : VFb;
#pragma unroll
    for (int j2 = 0; j2 < 8; j2++) {
      const int off = j2 * 2048 + t * 8;
      const int r = off >> 12;                 // 0..3 = h'*2 + kt'
      bf16* dst = outp + ((size_t)(b * NH + h0 + (r >> 1)) * 32 + kt0 + (r & 1)) * 4096 + (off & 4095);
      *(bf16x8*)dst = *(const bf16x8*)(L + off);
    }
  }
}

// ---------------- flash attention (causal), swapped 32x32, 4-wave split-k ----------------
// R18 verbatim (best attn: no LDS in k-loop, contiguous KF/VF 1KB loads,
// KVBLK=64, 4-wave in-block split-k, register diet, launch_bounds(256,3)).
__global__ __launch_bounds__(256, 3) void attn_kernel(const bf16* __restrict__ Q,
    const bf16* __restrict__ KF, const bf16* __restrict__ VF, bf16* __restrict__ AO) {
  __shared__ float Om[3][2048];   // [64 d-rows][32 q-cols] per publishing wave
  __shared__ float Ml[3][32];
  __shared__ float Ll[3][32];
  const int flat = blockIdx.x;                       // 0..1023
  const int flat2 = (flat & 7) * 128 + (flat >> 3);  // XCD-contiguous
  const int bh = flat2 >> 5;                         // 0..31 (4 per XCD)
  const int p = flat2 & 31;                          // pair index
  const int w = threadIdx.x >> 6;                    // wave 0..3
  const int lane = threadIdx.x & 63;
  const int q31 = lane & 31, hi = lane >> 5;
  const bf16* Qp = Q + (size_t)bh * SS * HD;
  const bf16* KFp = KF + (size_t)bh * SS * HD;       // 131072 bf16 per bh
  const bf16* VFp = VF + (size_t)bh * SS * HD;
  const float SCL = 0.125f * LOG2E;                  // exp2-domain scale

  auto run_chunk = [&](int qbase, int nt) {
    // Q frags (B-operand): lane: Q[qbase+q31][ds*16 + hi*8 + e], scaled
    bf16x8 qb[4];
#pragma unroll
    for (int ds = 0; ds < 4; ds++) {
      bf16x8 xq = *(const bf16x8*)(Qp + (size_t)(qbase + q31) * HD + ds * 16 + hi * 8);
#pragma unroll
      for (int e = 0; e < 8; e++) xq[e] = (bf16)((float)xq[e] * SCL);
      qb[ds] = xq;
    }
    float m_r = -3.0e38f, lsum = 0.f;
    f32x16 o0, o1;
#pragma unroll
    for (int e = 0; e < 16; e++) { o0[e] = 0.f; o1[e] = 0.f; }

    for (int tv = w; tv < nt; tv += 4) {
      const int k0 = tv * 64;
      const bf16* kt = KFp + (size_t)tv * 4096;
      const bf16* vt = VFp + (size_t)tv * 4096;
      // ---- QK^T (swapped: A=K, B=Q), K frags loaded 4-at-a-time ----
      f32x16 s0, s1;
#pragma unroll
      for (int e = 0; e < 16; e++) { s0[e] = 0.f; s1[e] = 0.f; }
      {
        bf16x8 kf[4];
#pragma unroll
        for (int ds = 0; ds < 4; ds++)
          kf[ds] = *(const bf16x8*)(kt + (size_t)(ds * 64 + lane) * 8);
#pragma unroll
        for (int ds = 0; ds < 4; ds++) s0 = mfma32(kf[ds], qb[ds], s0);
#pragma unroll
        for (int ds = 0; ds < 4; ds++)
          kf[ds] = *(const bf16x8*)(kt + (size_t)((4 + ds) * 64 + lane) * 8);
#pragma unroll
        for (int ds = 0; ds < 4; ds++) s1 = mfma32(kf[ds], qb[ds], s1);
      }
      // ---- causal mask (diagonal tiles only) ----
      if (k0 + 63 > qbase) {
        const int qg = qbase + q31;
#pragma unroll
        for (int r = 0; r < 16; r++) {
          const int kg = k0 + (r & 3) + 8 * (r >> 2) + 4 * hi;
          if (kg > qg)      s0[r] = -1.0e30f;
          if (kg + 32 > qg) s1[r] = -1.0e30f;
        }
      }
      // ---- in-lane online softmax (exp2 domain), tree reductions, defer-max ----
      {
        float a[16];
#pragma unroll
        for (int r = 0; r < 16; r++) a[r] = fmaxf(s0[r], s1[r]);
#pragma unroll
        for (int d = 8; d > 0; d >>= 1)
#pragma unroll
          for (int r = 0; r < d; r++) a[r] = fmaxf(a[r], a[r + d]);
        const float pm = fmaxf(a[0], __shfl_xor(a[0], 32));
        if (__any(pm > m_r + 8.0f)) {            // T13 defer-max, THR=8
          const float mnew = fmaxf(m_r, pm);
          const float alpha = __builtin_exp2f(m_r - mnew);
          lsum *= alpha;
#pragma unroll
          for (int e = 0; e < 16; e++) { o0[e] *= alpha; o1[e] *= alpha; }
          m_r = mnew;
        }
        float b[16];
#pragma unroll
        for (int r = 0; r < 16; r++) {
          s0[r] = __builtin_exp2f(s0[r] - m_r);
          s1[r] = __builtin_exp2f(s1[r] - m_r);
          b[r] = s0[r] + s1[r];
        }
#pragma unroll
        for (int d = 8; d > 0; d >>= 1)
#pragma unroll
          for (int r = 0; r < d; r++) b[r] += b[r + d];
        lsum += b[0] + __shfl_xor(b[0], 32);
      }
      // ---- pack P into B-frags (16 pack2 + 8 shfl_xor(32)) ----
      bf16x8 pf[4];
#pragma unroll
      for (int ks = 0; ks < 4; ks++) {
        const int rb = 8 * (ks & 1);
        float va0, va1, va2, va3, vb0, vb1, vb2, vb3;
        if (ks < 2) {
          va0 = s0[rb]; va1 = s0[rb + 1]; va2 = s0[rb + 2]; va3 = s0[rb + 3];
          vb0 = s0[rb + 4]; vb1 = s0[rb + 5]; vb2 = s0[rb + 6]; vb3 = s0[rb + 7];
        } else {
          va0 = s1[rb]; va1 = s1[rb + 1]; va2 = s1[rb + 2]; va3 = s1[rb + 3];
          vb0 = s1[rb + 4]; vb1 = s1[rb + 5]; vb2 = s1[rb + 6]; vb3 = s1[rb + 7];
        }
        const unsigned a01 = pack2(va0, va1), a23 = pack2(va2, va3);
        const unsigned b01 = pack2(vb0, vb1), b23 = pack2(vb2, vb3);
        const unsigned z1 = (unsigned)__shfl_xor((int)(hi ? a01 : b01), 32);
        const unsigned z2 = (unsigned)__shfl_xor((int)(hi ? a23 : b23), 32);
        union { unsigned u[4]; bf16x8 v; } cv;
        cv.u[0] = hi ? z1 : a01;
        cv.u[1] = hi ? z2 : a23;
        cv.u[2] = hi ? b01 : z1;
        cv.u[3] = hi ? b23 : z2;
        pf[ks] = cv.v;
      }
      // ---- PV (swapped: A=V, B=P); V frags loaded per-dt half ----
      {
        bf16x8 vf[4];
#pragma unroll
        for (int ks = 0; ks < 4; ks++)
          vf[ks] = *(const bf16x8*)(vt + (size_t)(ks * 64 + lane) * 8);
#pragma unroll
        for (int ks = 0; ks < 4; ks++) o0 = mfma32(vf[ks], pf[ks], o0);
#pragma unroll
        for (int ks = 0; ks < 4; ks++)
          vf[ks] = *(const bf16x8*)(vt + (size_t)((4 + ks) * 64 + lane) * 8);
#pragma unroll
        for (int ks = 0; ks < 4; ks++) o1 = mfma32(vf[ks], pf[ks], o1);
      }
    }
    // ---- publish partials (waves 1..3), merge + store (wave 0) ----
    __syncthreads();
    if (w) {
#pragma unroll
      for (int e = 0; e < 16; e++) {
        const int r = (e & 3) + 8 * (e >> 2) + 4 * hi;
        Om[w - 1][r * 32 + q31] = o0[e];
        Om[w - 1][(r + 32) * 32 + q31] = o1[e];
      }
      if (!hi) { Ml[w - 1][q31] = m_r; Ll[w - 1][q31] = lsum; }
    }
    __syncthreads();
    if (!w) {
      float mi_[3];
#pragma unroll
      for (int i = 0; i < 3; i++) mi_[i] = Ml[i][q31];
      float mm = fmaxf(fmaxf(m_r, mi_[0]), fmaxf(mi_[1], mi_[2]));
      const float aS = __builtin_exp2f(m_r - mm);
      float ai[3];
      float L2 = aS * lsum;
#pragma unroll
      for (int i = 0; i < 3; i++) {
        ai[i] = __builtin_exp2f(mi_[i] - mm);
        L2 += ai[i] * Ll[i][q31];
      }
      const float linv = 1.0f / L2;
      const int b = bh >> 4, h = bh & 15;
      const size_t rowb = ((size_t)(b * SS + qbase + q31)) * DM + h * HD;
#pragma unroll
      for (int g2 = 0; g2 < 4; g2++) {
        bf16x4 w0v, w1v;
#pragma unroll
        for (int j = 0; j < 4; j++) {
          const int e = 4 * g2 + j;
          const int r = j + 8 * g2 + 4 * hi;
          float v0 = aS * o0[e];
          float v1 = aS * o1[e];
#pragma unroll
          for (int i = 0; i < 3; i++) {
            v0 += ai[i] * Om[i][r * 32 + q31];
            v1 += ai[i] * Om[i][(r + 32) * 32 + q31];
          }
          w0v[j] = (bf16)(v0 * linv);
          w1v[j] = (bf16)(v1 * linv);
        }
        *(bf16x4*)(AO + rowb +      8 * g2 + 4 * hi) = w0v;
        *(bf16x4*)(AO + rowb + 32 + 8 * g2 + 4 * hi) = w1v;
      }
    }
    __syncthreads();   // protect merge buffers before next chunk's publishes
  };

  // pair p & 63-p: 33 tiles total per block, uniform across all blocks
  run_chunk(p * 32, p / 2 + 1);
  const int ph = 63 - p;
  run_chunk(ph * 32, ph / 2 + 1);
}

// ---------------- output projection -> fp32 d_out ----------------
__global__ __launch_bounds__(256, 2) void oproj_kernel(const bf16* __restrict__ AO,
    const bf16* __restrict__ wob, float* __restrict__ out) {
  __shared__ __align__(16) bf16 L[24576];
  f32x4 acc[4][4];
  const int rowA0 = blockIdx.y * 128, rowB0 = blockIdx.x * 128;
  gemm_bt_128(AO, wob, rowA0, rowB0, acc, L);
  const int t = threadIdx.x, w = t >> 6, lane = t & 63;
  const int wr = w >> 1, wc = w & 1, g = lane >> 4, c = lane & 15;
#pragma unroll
  for (int mi = 0; mi < 4; mi++)
#pragma unroll
    for (int ni = 0; ni < 4; ni++) {
      const int ncol = rowB0 + wc * 64 + ni * 16 + c;
#pragma unroll
      for (int j = 0; j < 4; j++) {
        const int mrow = rowA0 + wr * 64 + mi * 16 + 4 * g + j;
        out[(size_t)mrow * DM + ncol] = acc[mi][ni][j];
      }
    }
}

extern "C" void kernel_launch(void* const* d_in, const int* in_sizes, int n_in,
                              void* d_out, int out_size, void* d_ws, size_t ws_size,
                              hipStream_t stream) {
  const float* x  = (const float*)d_in[0];
  const float* wq = (const float*)d_in[1];
  const float* wk = (const float*)d_in[2];
  const float* wv = (const float*)d_in[3];
  const float* wo = (const float*)d_in[4];
  const int*   pos = (const int*)d_in[5];
  char* ws = (char*)d_ws;
  bf16* xb   = (bf16*)(ws + OFF_XB);
  bf16* wqkv = (bf16*)(ws + OFF_WQKV);
  bf16* wob  = (bf16*)(ws + OFF_WO);
  fx2*  tab  = (fx2*)(ws + OFF_TAB);
  bf16* Qb   = (bf16*)(ws + OFF_Q);
  bf16* KFb  = (bf16*)(ws + OFF_KF);
  bf16* VFb  = (bf16*)(ws + OFF_VF);
  bf16* AOb  = (bf16*)(ws + OFF_AO);

  hipLaunchKernelGGL(prep_kernel, dim3(2048), dim3(256), 0, stream,
                     x, wq, wk, wv, wo, pos, xb, wqkv, wob, tab);
  hipLaunchKernelGGL(qkv_kernel, dim3(24, 32), dim3(256), 0, stream,
                     xb, wqkv, tab, Qb, KFb, VFb);
  hipLaunchKernelGGL(attn_kernel, dim3(1024), dim3(256), 0, stream,
                     Qb, KFb, VFb, AOb);
  hipLaunchKernelGGL(oproj_kernel, dim3(8, 32), dim3(256), 0, stream,
                     AOb, wob, (float*)d_out);
}